// Round 20
// baseline (258.343 us; speedup 1.0000x reference)
//
#include <hip/hip_runtime.h>
#include <hip/hip_bf16.h>

typedef __attribute__((ext_vector_type(8))) __bf16 bf16x8;
typedef __attribute__((ext_vector_type(4))) __bf16 bf16x4;
typedef __attribute__((ext_vector_type(4))) float f32x4;

#define AS1(p) ((__attribute__((address_space(1))) void*)(p))
#define AS3(p) ((__attribute__((address_space(3))) void*)(p))

// ---------------------------------------------------------------- f32 -> bf16
__global__ void f2b_kernel(const float4* __restrict__ in, bf16x4* __restrict__ out, int n4) {
    int idx = blockIdx.x * blockDim.x + threadIdx.x;
    int stride = gridDim.x * blockDim.x;
    for (int i = idx; i < n4; i += stride) {
        float4 v = in[i];
        bf16x4 o;
        o[0] = (__bf16)v.x; o[1] = (__bf16)v.y; o[2] = (__bf16)v.z; o[3] = (__bf16)v.w;
        out[i] = o;
    }
}

// two-buffer variant (weights): one launch instead of two
__global__ void f2b2_kernel(const float4* __restrict__ a, bf16x4* __restrict__ oa, int na4,
                            const float4* __restrict__ b, bf16x4* __restrict__ ob, int nb4) {
    int idx = blockIdx.x * blockDim.x + threadIdx.x;
    int stride = gridDim.x * blockDim.x;
    for (int i = idx; i < na4 + nb4; i += stride) {
        const float4 v = (i < na4) ? a[i] : b[i - na4];
        bf16x4 o;
        o[0] = (__bf16)v.x; o[1] = (__bf16)v.y; o[2] = (__bf16)v.z; o[3] = (__bf16)v.w;
        if (i < na4) oa[i] = o; else ob[i - na4] = o;
    }
}

// ---------------------------------------------------------------- 256x256 pipelined GEMM (r13/r15 best, frozen)
// C = A @ B^T. 512 thr = 8 waves (2M x 4N), per-wave 128x64 output, acc[8][4].
// K in 32-wide slots; 4-slot LDS ring staged 3 ahead (counted vmcnt(8), 1 barrier/slot).
// NOTE (r19 lesson): vmcnt MUST precede s_barrier — the barrier publishes other
// waves' DMA completion; 2-slot rings can't support counted vmcnt (stage-ahead 1).
// Pair swizzle (conflict-free, r13): chunk = fk ^ ((row>>1)&3); DMA source pre-swizzled.
// MODE 0: qkv. q,k -> Cb[row][2048] + fused RMSNorm (q * Dh^-0.5 * log2e); v -> Vt.
// MODE 1: f32 out + bias, ldc = N.
template<int MODE>
__global__ __launch_bounds__(512, 2)
void gemm256(const __bf16* __restrict__ A, const __bf16* __restrict__ Bw,
             const float* __restrict__ bias, const float* __restrict__ qw,
             const float* __restrict__ kw, float* __restrict__ Cf,
             __bf16* __restrict__ Cb, __bf16* __restrict__ Vt,
             int M, int K, int nbn, int ldc)
{
    __shared__ __bf16 Asl[4][256 * 32];
    __shared__ __bf16 Bsl[4][256 * 32];
    const int tid = threadIdx.x, l = tid & 63, w = tid >> 6;
    const int fr = l & 15, fk = l >> 4;

    const int cpx = gridDim.x >> 3;
    const int wg = (blockIdx.x & 7) * cpx + (blockIdx.x >> 3);
    const int bm = wg / nbn, bn = wg % nbn;

    const __bf16* Ag = A + (size_t)bm * 256 * K;
    const __bf16* Bg = Bw + (size_t)bn * 256 * K;

    const int arow = tid >> 2;
    const int uch = (tid & 3) ^ ((arow >> 1) & 3);
    const size_t ga = (size_t)arow * K + uch * 8;
    const size_t ga2 = ga + (size_t)128 * K;

    const int axc = (fk ^ ((fr >> 1) & 3)) * 16;
    int aoff[8], boff[4];
    #pragma unroll
    for (int m = 0; m < 8; ++m)
        aoff[m] = ((w >> 2) * 128 + m * 16 + fr) * 64 + axc;
    #pragma unroll
    for (int n = 0; n < 4; ++n)
        boff[n] = ((w & 3) * 64 + n * 16 + fr) * 64 + axc;

    f32x4 acc[8][4] = {};

#define STAGE256(S) do {                                                                    \
    const int sb_ = (S) & 3;                                                                \
    __builtin_amdgcn_global_load_lds(AS1(Ag + (size_t)(S) * 32 + ga),                       \
        AS3((char*)&Asl[sb_][0] + tid * 16), 16, 0, 0);                                     \
    __builtin_amdgcn_global_load_lds(AS1(Ag + (size_t)(S) * 32 + ga2),                      \
        AS3((char*)&Asl[sb_][0] + tid * 16 + 8192), 16, 0, 0);                              \
    __builtin_amdgcn_global_load_lds(AS1(Bg + (size_t)(S) * 32 + ga),                       \
        AS3((char*)&Bsl[sb_][0] + tid * 16), 16, 0, 0);                                     \
    __builtin_amdgcn_global_load_lds(AS1(Bg + (size_t)(S) * 32 + ga2),                      \
        AS3((char*)&Bsl[sb_][0] + tid * 16 + 8192), 16, 0, 0);                              \
} while (0)

#define PHASE256(S, VMSTR, DOSTAGE) do {                                                    \
    asm volatile("s_waitcnt vmcnt(" VMSTR ")" ::: "memory");                                \
    __builtin_amdgcn_s_barrier();                                                           \
    __builtin_amdgcn_sched_barrier(0);                                                      \
    const int pb_ = (S) & 3;                                                                \
    bf16x8 af[8], bfv[4];                                                                   \
    _Pragma("unroll")                                                                       \
    for (int m = 0; m < 8; ++m)                                                             \
        af[m] = *(const bf16x8*)((const char*)&Asl[pb_][0] + aoff[m]);                      \
    _Pragma("unroll")                                                                       \
    for (int n = 0; n < 4; ++n)                                                             \
        bfv[n] = *(const bf16x8*)((const char*)&Bsl[pb_][0] + boff[n]);                     \
    if (DOSTAGE) STAGE256((S) + 3);                                                         \
    __builtin_amdgcn_s_setprio(1);                                                          \
    _Pragma("unroll")                                                                       \
    for (int m = 0; m < 8; ++m)                                                             \
        _Pragma("unroll")                                                                   \
        for (int n = 0; n < 4; ++n)                                                         \
            acc[m][n] = __builtin_amdgcn_mfma_f32_16x16x32_bf16(af[m], bfv[n], acc[m][n], 0, 0, 0); \
    __builtin_amdgcn_s_setprio(0);                                                          \
} while (0)

    const int S = K >> 5;
    STAGE256(0); STAGE256(1); STAGE256(2);
    for (int s = 0; s < S - 2; ++s)
        PHASE256(s, "8", (s + 3 < S));
    PHASE256(S - 2, "4", false);
    PHASE256(S - 1, "0", false);
#undef PHASE256
#undef STAGE256

    // ---------------- epilogue: C/D layout col = fr, row = fk*4 + r
    const int rb0 = bm * 256 + (w >> 2) * 128 + fk * 4;
    const int cb0 = bn * 256 + (w & 3) * 64;

    if (MODE == 1) {
        #pragma unroll
        for (int m = 0; m < 8; ++m)
            #pragma unroll
            for (int n = 0; n < 4; ++n) {
                const int col = cb0 + n * 16 + fr;
                const float bv = bias[col];
                #pragma unroll
                for (int r = 0; r < 4; ++r)
                    Cf[(size_t)(rb0 + m * 16 + r) * ldc + col] = acc[m][n][r] + bv;
            }
    } else {
        const int sect = bn >> 2;          // 0=q, 1=k, 2=v (nbn=12)
        if (sect < 2) {
            const float* wp = (sect == 0) ? qw : kw;
            float wn[4];
            #pragma unroll
            for (int n = 0; n < 4; ++n) wn[n] = wp[((w & 3) * 64 + n * 16 + fr) & 63];
            #pragma unroll
            for (int m = 0; m < 8; ++m) {
                float sc[4];
                #pragma unroll
                for (int r = 0; r < 4; ++r) {
                    float ps = 0.f;
                    #pragma unroll
                    for (int n = 0; n < 4; ++n) ps += acc[m][n][r] * acc[m][n][r];
                    ps += __shfl_xor(ps, 1); ps += __shfl_xor(ps, 2);
                    ps += __shfl_xor(ps, 4); ps += __shfl_xor(ps, 8);
                    sc[r] = rsqrtf(ps * (1.0f / 64.0f) + 1e-6f);
                    if (sect == 0) sc[r] *= 0.18033688011112042f;   // 0.125 * log2(e)
                }
                #pragma unroll
                for (int n = 0; n < 4; ++n)
                    #pragma unroll
                    for (int r = 0; r < 4; ++r)
                        Cb[(size_t)(rb0 + m * 16 + r) * ldc + cb0 + n * 16 + fr] =
                            (__bf16)(acc[m][n][r] * sc[r] * wn[n]);
            }
        } else {
            // v -> Vt[((b*16+h)*64+d)*1024 + token], token-contiguous 8B stores
            #pragma unroll
            for (int m = 0; m < 8; ++m) {
                const int tok = rb0 + m * 16;
                const int b = tok >> 10, ntok = tok & 1023;
                #pragma unroll
                for (int n = 0; n < 4; ++n) {
                    const int vd = (bn - 8) * 256 + (w & 3) * 64 + n * 16 + fr;
                    bf16x4 pk;
                    #pragma unroll
                    for (int r = 0; r < 4; ++r) pk[r] = (__bf16)acc[m][n][r];
                    *(bf16x4*)&Vt[((size_t)((b * 16 + (vd >> 6)) * 64 + (vd & 63))) * 1024 + ntok] = pk;
                }
            }
        }
    }
}

// ---------------------------------------------------------------- flash attention v12 (r18, frozen)
// 4 q-tiles/wave (256 q-rows/block, grid 1024), 2 blocks/CU, kt-pair ring staging.
// Explicit software pipeline over j = kh*4+qi; P parity-buffered; no-max exp2 softmax;
// ls via MFMA against ones fragment.
__global__ __launch_bounds__(256, 2)
void attn_kernel(const __bf16* __restrict__ qkv, const __bf16* __restrict__ vt,
                 __bf16* __restrict__ ao)
{
    __shared__ __bf16 Ks[4][64 * 64];       // 32 KB, ring of 4 kt tiles
    __shared__ __bf16 Vs[4][64 * 64];       // 32 KB
    __shared__ __bf16 Pl[4][2 * 16 * 64];   // 16 KB, per-wave parity-buffered P
    const int tid = threadIdx.x, l = tid & 63, w = tid >> 6;
    const int fr = l & 15, fk = l >> 4;
    const int sw = (fr & 7) << 4;

    const int bi = blockIdx.x;
    const int L = (bi & 7) * 128 + (bi >> 3);
    const int qb = L & 3, h = (L >> 2) & 15, b = L >> 6;

    const __bf16* Kg = qkv + (size_t)b * 1024 * 2048 + 1024 + h * 64;
    const __bf16* Vg = vt + (size_t)((b * 16 + h) * 64) * 1024;
    const int srow = tid >> 3, scp = tid & 7;

    const int c8 = (scp ^ (srow & 7)) * 8;
    const size_t kO0 = (size_t)srow * 2048 + c8, kO1 = kO0 + 32 * 2048;
    const size_t vO0 = (size_t)srow * 1024 + c8, vO1 = vO0 + 32 * 1024;
    char* ksd = (char*)&Ks[0][0] + tid * 16;
    char* vsd = (char*)&Vs[0][0] + tid * 16;

#define STAGE(KT) do {                                                                    \
    char* dk_ = ksd + ((KT) & 3) * 8192;                                                  \
    char* dv_ = vsd + ((KT) & 3) * 8192;                                                  \
    __builtin_amdgcn_global_load_lds(AS1(Kg + (size_t)(KT) * 131072 + kO0), AS3(dk_), 16, 0, 0); \
    __builtin_amdgcn_global_load_lds(AS1(Kg + (size_t)(KT) * 131072 + kO1), AS3(dk_ + 4096), 16, 0, 0); \
    __builtin_amdgcn_global_load_lds(AS1(Vg + (KT) * 64 + vO0), AS3(dv_), 16, 0, 0);      \
    __builtin_amdgcn_global_load_lds(AS1(Vg + (KT) * 64 + vO1), AS3(dv_ + 4096), 16, 0, 0); \
} while (0)

    STAGE(0); STAGE(1);     // pair 0 in flight (8 loads)

    const int qrow0 = b * 1024 + qb * 256 + w * 64;
    bf16x8 qf[4][2];
    #pragma unroll
    for (int qi = 0; qi < 4; ++qi)
        #pragma unroll
        for (int dc = 0; dc < 2; ++dc)
            qf[qi][dc] = *(const bf16x8*)&qkv[(size_t)(qrow0 + qi * 16 + fr) * 2048
                                              + h * 64 + dc * 32 + fk * 8];

    const int kb0 = fr * 128 + ((fk ^ (fr & 7)) * 16);
    const int kb1 = fr * 128 + (((4 + fk) ^ (fr & 7)) * 16);
    const char* KsB = (const char*)&Ks[0][0];
    const char* VsB = (const char*)&Vs[0][0];

    char* Pw = (char*)&Pl[w][0];
    const int pw0 = (fr * 128 + 0 * 32 + fk * 8) ^ sw;
    const int pw1 = (fr * 128 + 1 * 32 + fk * 8) ^ sw;
    const int pw2 = (fr * 128 + 2 * 32 + fk * 8) ^ sw;
    const int pw3 = (fr * 128 + 3 * 32 + fk * 8) ^ sw;
    const int pr0 = (fr * 128 + 0 * 64 + fk * 16) ^ sw;
    const int pr1 = (fr * 128 + 1 * 64 + fk * 16) ^ sw;

    bf16x8 onesf;
    #pragma unroll
    for (int i = 0; i < 8; ++i) onesf[i] = (__bf16)1.0f;

    f32x4 oacc[4][4] = {};
    f32x4 lacc[4] = {};

#define QK8(SA, QI, CB) do {                                                              \
    _Pragma("unroll")                                                                     \
    for (int n_ = 0; n_ < 4; ++n_) {                                                      \
        bf16x8 k0_ = *(const bf16x8*)(KsB + (CB) + kb0 + n_ * 2048);                      \
        bf16x8 k1_ = *(const bf16x8*)(KsB + (CB) + kb1 + n_ * 2048);                      \
        SA[n_] = __builtin_amdgcn_mfma_f32_16x16x32_bf16(k0_, qf[QI][0], SA[n_], 0, 0, 0);\
        SA[n_] = __builtin_amdgcn_mfma_f32_16x16x32_bf16(k1_, qf[QI][1], SA[n_], 0, 0, 0);\
    } } while (0)

#define EXPW(SA, PQ) do {                                                                 \
    _Pragma("unroll")                                                                     \
    for (int n_ = 0; n_ < 4; ++n_) {                                                      \
        bf16x4 pk_;                                                                       \
        _Pragma("unroll")                                                                 \
        for (int r_ = 0; r_ < 4; ++r_)                                                    \
            pk_[r_] = (__bf16)__builtin_amdgcn_exp2f(SA[n_][r_]);                         \
        const int pwn_ = (n_ == 0) ? pw0 : (n_ == 1) ? pw1 : (n_ == 2) ? pw2 : pw3;       \
        *(bf16x4*)(Pw + (PQ) + pwn_) = pk_;                                               \
    } } while (0)

    for (int p = 0; p < 8; ++p) {
        asm volatile("s_waitcnt vmcnt(0)" ::: "memory");
        __builtin_amdgcn_s_barrier();
        __builtin_amdgcn_sched_barrier(0);
        if (p < 7) { STAGE(2 * p + 2); STAGE(2 * p + 3); }

        const int cb0 = ((p & 1) << 1) * 8192;
        const int cb1 = cb0 + 8192;

        bf16x8 vf[4][2];
        #pragma unroll
        for (int nd = 0; nd < 4; ++nd) {
            vf[nd][0] = *(const bf16x8*)(VsB + cb0 + kb0 + nd * 2048);
            vf[nd][1] = *(const bf16x8*)(VsB + cb0 + kb1 + nd * 2048);
        }

        {
            f32x4 s0[4] = {};
            QK8(s0, 0, cb0);
            EXPW(s0, 0);
        }

        #pragma unroll
        for (int j = 0; j < 8; ++j) {
            const int qi = j & 3;
            const int pq = (j & 1) * 2048;
            const int pqn = ((j + 1) & 1) * 2048;
            const int cbn = (j + 1 < 4) ? cb0 : cb1;

            bf16x8 pf0 = *(const bf16x8*)(Pw + pq + pr0);
            bf16x8 pf1 = *(const bf16x8*)(Pw + pq + pr1);

            if (j == 4) {
                #pragma unroll
                for (int nd = 0; nd < 4; ++nd) {
                    vf[nd][0] = *(const bf16x8*)(VsB + cb1 + kb0 + nd * 2048);
                    vf[nd][1] = *(const bf16x8*)(VsB + cb1 + kb1 + nd * 2048);
                }
            }

            f32x4 sn[4] = {};
            if (j < 7) QK8(sn, (j + 1) & 3, cbn);

            lacc[qi] = __builtin_amdgcn_mfma_f32_16x16x32_bf16(pf0, onesf, lacc[qi], 0, 0, 0);
            lacc[qi] = __builtin_amdgcn_mfma_f32_16x16x32_bf16(pf1, onesf, lacc[qi], 0, 0, 0);
            #pragma unroll
            for (int nd = 0; nd < 4; ++nd) {
                oacc[qi][nd] = __builtin_amdgcn_mfma_f32_16x16x32_bf16(pf0, vf[nd][0],
                                                                       oacc[qi][nd], 0, 0, 0);
                oacc[qi][nd] = __builtin_amdgcn_mfma_f32_16x16x32_bf16(pf1, vf[nd][1],
                                                                       oacc[qi][nd], 0, 0, 0);
            }

            if (j < 7) EXPW(sn, pqn);
        }
    }

    #pragma unroll
    for (int qi = 0; qi < 4; ++qi) {
        float inv[4];
        #pragma unroll
        for (int r = 0; r < 4; ++r)
            inv[r] = __builtin_amdgcn_rcpf(lacc[qi][r]);
        #pragma unroll
        for (int nd = 0; nd < 4; ++nd)
            #pragma unroll
            for (int r = 0; r < 4; ++r)
                ao[(size_t)(qrow0 + qi * 16 + fk * 4 + r) * 1024 + h * 64 + nd * 16 + fr] =
                    (__bf16)(oacc[qi][nd][r] * inv[r]);
    }
#undef QK8
#undef EXPW
#undef STAGE
}

// ---------------------------------------------------------------- launch
extern "C" void kernel_launch(void* const* d_in, const int* in_sizes, int n_in,
                              void* d_out, int out_size, void* d_ws, size_t ws_size,
                              hipStream_t stream)
{
    const float* x      = (const float*)d_in[0];
    const float* qkv_w  = (const float*)d_in[1];
    const float* proj_w = (const float*)d_in[2];
    const float* proj_b = (const float*)d_in[3];
    const float* qnw    = (const float*)d_in[4];
    const float* knw    = (const float*)d_in[5];

    char* ws = (char*)d_ws;
    __bf16* xb    = (__bf16*)(ws);                      // 32 MB
    __bf16* wqkv  = (__bf16*)(ws + 33554432);           // 6 MB
    __bf16* wproj = (__bf16*)(ws + 39845888);           // 2 MB
    __bf16* qkv   = (__bf16*)(ws + 41943040);           // 64 MB  [16384][2048] q,k only
    __bf16* vt    = (__bf16*)(ws + 109051904);          // 32 MB  [b][h][d][n]
    __bf16* ao    = (__bf16*)(ws + 142606336);          // 32 MB

    f2b_kernel<<<2048, 256, 0, stream>>>((const float4*)x, (bf16x4*)xb, 16777216 / 4);
    f2b2_kernel<<<2048, 256, 0, stream>>>((const float4*)qkv_w,  (bf16x4*)wqkv,  3145728 / 4,
                                          (const float4*)proj_w, (bf16x4*)wproj, 1048576 / 4);

    gemm256<0><<<768, 512, 0, stream>>>(xb, wqkv, nullptr, qnw, knw,
                                        nullptr, qkv, vt, 16384, 1024, 12, 2048);
    attn_kernel<<<1024, 256, 0, stream>>>(qkv, vt, ao);
    gemm256<1><<<256, 512, 0, stream>>>(ao, wproj, proj_b, nullptr, nullptr,
                                        (float*)d_out, nullptr, nullptr, 16384, 1024, 4, 1024);
}

// Round 22
// 253.383 us; speedup vs baseline: 1.0196x; 1.0196x over previous
//
#include <hip/hip_runtime.h>
#include <hip/hip_bf16.h>

typedef __attribute__((ext_vector_type(8))) __bf16 bf16x8;
typedef __attribute__((ext_vector_type(4))) __bf16 bf16x4;
typedef __attribute__((ext_vector_type(4))) float f32x4;

#define AS1(p) ((__attribute__((address_space(1))) void*)(p))
#define AS3(p) ((__attribute__((address_space(3))) void*)(p))

// ---------------------------------------------------------------- f32 -> bf16
__global__ void f2b_kernel(const float4* __restrict__ in, bf16x4* __restrict__ out, int n4) {
    int idx = blockIdx.x * blockDim.x + threadIdx.x;
    int stride = gridDim.x * blockDim.x;
    for (int i = idx; i < n4; i += stride) {
        float4 v = in[i];
        bf16x4 o;
        o[0] = (__bf16)v.x; o[1] = (__bf16)v.y; o[2] = (__bf16)v.z; o[3] = (__bf16)v.w;
        out[i] = o;
    }
}

// two-buffer variant (weights): one launch instead of two
__global__ void f2b2_kernel(const float4* __restrict__ a, bf16x4* __restrict__ oa, int na4,
                            const float4* __restrict__ b, bf16x4* __restrict__ ob, int nb4) {
    int idx = blockIdx.x * blockDim.x + threadIdx.x;
    int stride = gridDim.x * blockDim.x;
    for (int i = idx; i < na4 + nb4; i += stride) {
        const float4 v = (i < na4) ? a[i] : b[i - na4];
        bf16x4 o;
        o[0] = (__bf16)v.x; o[1] = (__bf16)v.y; o[2] = (__bf16)v.z; o[3] = (__bf16)v.w;
        if (i < na4) oa[i] = o; else ob[i - na4] = o;
    }
}

// ---------------------------------------------------------------- 256x256 pipelined GEMM (r13/r15 best, frozen)
// C = A @ B^T. 512 thr = 8 waves (2M x 4N), per-wave 128x64 output, acc[8][4].
// K in 32-wide slots; 4-slot LDS ring staged 3 ahead (counted vmcnt(8), 1 barrier/slot).
// The vmcnt->s_barrier pair is load-bearing TWICE (r19/r21 lessons): it publishes
// cross-wave DMA completion AND bounds inter-wave drift below the ring distance.
// Pair swizzle (conflict-free, r13): chunk = fk ^ ((row>>1)&3); DMA source pre-swizzled.
// MODE 0: qkv. q,k -> Cb[row][2048] + fused RMSNorm (q * Dh^-0.5 * log2e); v -> Vt.
// MODE 1: f32 out + bias, ldc = N.
template<int MODE>
__global__ __launch_bounds__(512, 2)
void gemm256(const __bf16* __restrict__ A, const __bf16* __restrict__ Bw,
             const float* __restrict__ bias, const float* __restrict__ qw,
             const float* __restrict__ kw, float* __restrict__ Cf,
             __bf16* __restrict__ Cb, __bf16* __restrict__ Vt,
             int M, int K, int nbn, int ldc)
{
    __shared__ __bf16 Asl[4][256 * 32];
    __shared__ __bf16 Bsl[4][256 * 32];
    const int tid = threadIdx.x, l = tid & 63, w = tid >> 6;
    const int fr = l & 15, fk = l >> 4;

    const int cpx = gridDim.x >> 3;
    const int wg = (blockIdx.x & 7) * cpx + (blockIdx.x >> 3);
    const int bm = wg / nbn, bn = wg % nbn;

    const __bf16* Ag = A + (size_t)bm * 256 * K;
    const __bf16* Bg = Bw + (size_t)bn * 256 * K;

    const int arow = tid >> 2;
    const int uch = (tid & 3) ^ ((arow >> 1) & 3);
    const size_t ga = (size_t)arow * K + uch * 8;
    const size_t ga2 = ga + (size_t)128 * K;

    const int axc = (fk ^ ((fr >> 1) & 3)) * 16;
    int aoff[8], boff[4];
    #pragma unroll
    for (int m = 0; m < 8; ++m)
        aoff[m] = ((w >> 2) * 128 + m * 16 + fr) * 64 + axc;
    #pragma unroll
    for (int n = 0; n < 4; ++n)
        boff[n] = ((w & 3) * 64 + n * 16 + fr) * 64 + axc;

    f32x4 acc[8][4] = {};

#define STAGE256(S) do {                                                                    \
    const int sb_ = (S) & 3;                                                                \
    __builtin_amdgcn_global_load_lds(AS1(Ag + (size_t)(S) * 32 + ga),                       \
        AS3((char*)&Asl[sb_][0] + tid * 16), 16, 0, 0);                                     \
    __builtin_amdgcn_global_load_lds(AS1(Ag + (size_t)(S) * 32 + ga2),                      \
        AS3((char*)&Asl[sb_][0] + tid * 16 + 8192), 16, 0, 0);                              \
    __builtin_amdgcn_global_load_lds(AS1(Bg + (size_t)(S) * 32 + ga),                       \
        AS3((char*)&Bsl[sb_][0] + tid * 16), 16, 0, 0);                                     \
    __builtin_amdgcn_global_load_lds(AS1(Bg + (size_t)(S) * 32 + ga2),                      \
        AS3((char*)&Bsl[sb_][0] + tid * 16 + 8192), 16, 0, 0);                              \
} while (0)

#define PHASE256(S, VMSTR, DOSTAGE) do {                                                    \
    asm volatile("s_waitcnt vmcnt(" VMSTR ")" ::: "memory");                                \
    __builtin_amdgcn_s_barrier();                                                           \
    __builtin_amdgcn_sched_barrier(0);                                                      \
    const int pb_ = (S) & 3;                                                                \
    bf16x8 af[8], bfv[4];                                                                   \
    _Pragma("unroll")                                                                       \
    for (int m = 0; m < 8; ++m)                                                             \
        af[m] = *(const bf16x8*)((const char*)&Asl[pb_][0] + aoff[m]);                      \
    _Pragma("unroll")                                                                       \
    for (int n = 0; n < 4; ++n)                                                             \
        bfv[n] = *(const bf16x8*)((const char*)&Bsl[pb_][0] + boff[n]);                     \
    if (DOSTAGE) STAGE256((S) + 3);                                                         \
    __builtin_amdgcn_s_setprio(1);                                                          \
    _Pragma("unroll")                                                                       \
    for (int m = 0; m < 8; ++m)                                                             \
        _Pragma("unroll")                                                                   \
        for (int n = 0; n < 4; ++n)                                                         \
            acc[m][n] = __builtin_amdgcn_mfma_f32_16x16x32_bf16(af[m], bfv[n], acc[m][n], 0, 0, 0); \
    __builtin_amdgcn_s_setprio(0);                                                          \
} while (0)

    const int S = K >> 5;
    STAGE256(0); STAGE256(1); STAGE256(2);
    for (int s = 0; s < S - 2; ++s)
        PHASE256(s, "8", (s + 3 < S));
    PHASE256(S - 2, "4", false);
    PHASE256(S - 1, "0", false);
#undef PHASE256
#undef STAGE256

    // ---------------- epilogue: C/D layout col = fr, row = fk*4 + r
    const int rb0 = bm * 256 + (w >> 2) * 128 + fk * 4;
    const int cb0 = bn * 256 + (w & 3) * 64;

    if (MODE == 1) {
        #pragma unroll
        for (int m = 0; m < 8; ++m)
            #pragma unroll
            for (int n = 0; n < 4; ++n) {
                const int col = cb0 + n * 16 + fr;
                const float bv = bias[col];
                #pragma unroll
                for (int r = 0; r < 4; ++r)
                    Cf[(size_t)(rb0 + m * 16 + r) * ldc + col] = acc[m][n][r] + bv;
            }
    } else {
        const int sect = bn >> 2;          // 0=q, 1=k, 2=v (nbn=12)
        if (sect < 2) {
            const float* wp = (sect == 0) ? qw : kw;
            float wn[4];
            #pragma unroll
            for (int n = 0; n < 4; ++n) wn[n] = wp[((w & 3) * 64 + n * 16 + fr) & 63];
            #pragma unroll
            for (int m = 0; m < 8; ++m) {
                float sc[4];
                #pragma unroll
                for (int r = 0; r < 4; ++r) {
                    float ps = 0.f;
                    #pragma unroll
                    for (int n = 0; n < 4; ++n) ps += acc[m][n][r] * acc[m][n][r];
                    ps += __shfl_xor(ps, 1); ps += __shfl_xor(ps, 2);
                    ps += __shfl_xor(ps, 4); ps += __shfl_xor(ps, 8);
                    sc[r] = rsqrtf(ps * (1.0f / 64.0f) + 1e-6f);
                    if (sect == 0) sc[r] *= 0.18033688011112042f;   // 0.125 * log2(e)
                }
                #pragma unroll
                for (int n = 0; n < 4; ++n)
                    #pragma unroll
                    for (int r = 0; r < 4; ++r)
                        Cb[(size_t)(rb0 + m * 16 + r) * ldc + cb0 + n * 16 + fr] =
                            (__bf16)(acc[m][n][r] * sc[r] * wn[n]);
            }
        } else {
            // v -> Vt[((b*16+h)*64+d)*1024 + token], token-contiguous 8B stores
            #pragma unroll
            for (int m = 0; m < 8; ++m) {
                const int tok = rb0 + m * 16;
                const int b = tok >> 10, ntok = tok & 1023;
                #pragma unroll
                for (int n = 0; n < 4; ++n) {
                    const int vd = (bn - 8) * 256 + (w & 3) * 64 + n * 16 + fr;
                    bf16x4 pk;
                    #pragma unroll
                    for (int r = 0; r < 4; ++r) pk[r] = (__bf16)acc[m][n][r];
                    *(bf16x4*)&Vt[((size_t)((b * 16 + (vd >> 6)) * 64 + (vd & 63))) * 1024 + ntok] = pk;
                }
            }
        }
    }
}

// ---------------------------------------------------------------- flash attention v12 (r18, frozen)
// 4 q-tiles/wave (256 q-rows/block, grid 1024), 2 blocks/CU, kt-pair ring staging.
// Explicit software pipeline over j = kh*4+qi; P parity-buffered; no-max exp2 softmax;
// ls via MFMA against ones fragment.
__global__ __launch_bounds__(256, 2)
void attn_kernel(const __bf16* __restrict__ qkv, const __bf16* __restrict__ vt,
                 __bf16* __restrict__ ao)
{
    __shared__ __bf16 Ks[4][64 * 64];       // 32 KB, ring of 4 kt tiles
    __shared__ __bf16 Vs[4][64 * 64];       // 32 KB
    __shared__ __bf16 Pl[4][2 * 16 * 64];   // 16 KB, per-wave parity-buffered P
    const int tid = threadIdx.x, l = tid & 63, w = tid >> 6;
    const int fr = l & 15, fk = l >> 4;
    const int sw = (fr & 7) << 4;

    const int bi = blockIdx.x;
    const int L = (bi & 7) * 128 + (bi >> 3);
    const int qb = L & 3, h = (L >> 2) & 15, b = L >> 6;

    const __bf16* Kg = qkv + (size_t)b * 1024 * 2048 + 1024 + h * 64;
    const __bf16* Vg = vt + (size_t)((b * 16 + h) * 64) * 1024;
    const int srow = tid >> 3, scp = tid & 7;

    const int c8 = (scp ^ (srow & 7)) * 8;
    const size_t kO0 = (size_t)srow * 2048 + c8, kO1 = kO0 + 32 * 2048;
    const size_t vO0 = (size_t)srow * 1024 + c8, vO1 = vO0 + 32 * 1024;
    char* ksd = (char*)&Ks[0][0] + tid * 16;
    char* vsd = (char*)&Vs[0][0] + tid * 16;

#define STAGE(KT) do {                                                                    \
    char* dk_ = ksd + ((KT) & 3) * 8192;                                                  \
    char* dv_ = vsd + ((KT) & 3) * 8192;                                                  \
    __builtin_amdgcn_global_load_lds(AS1(Kg + (size_t)(KT) * 131072 + kO0), AS3(dk_), 16, 0, 0); \
    __builtin_amdgcn_global_load_lds(AS1(Kg + (size_t)(KT) * 131072 + kO1), AS3(dk_ + 4096), 16, 0, 0); \
    __builtin_amdgcn_global_load_lds(AS1(Vg + (KT) * 64 + vO0), AS3(dv_), 16, 0, 0);      \
    __builtin_amdgcn_global_load_lds(AS1(Vg + (KT) * 64 + vO1), AS3(dv_ + 4096), 16, 0, 0); \
} while (0)

    STAGE(0); STAGE(1);     // pair 0 in flight (8 loads)

    const int qrow0 = b * 1024 + qb * 256 + w * 64;
    bf16x8 qf[4][2];
    #pragma unroll
    for (int qi = 0; qi < 4; ++qi)
        #pragma unroll
        for (int dc = 0; dc < 2; ++dc)
            qf[qi][dc] = *(const bf16x8*)&qkv[(size_t)(qrow0 + qi * 16 + fr) * 2048
                                              + h * 64 + dc * 32 + fk * 8];

    const int kb0 = fr * 128 + ((fk ^ (fr & 7)) * 16);
    const int kb1 = fr * 128 + (((4 + fk) ^ (fr & 7)) * 16);
    const char* KsB = (const char*)&Ks[0][0];
    const char* VsB = (const char*)&Vs[0][0];

    char* Pw = (char*)&Pl[w][0];
    const int pw0 = (fr * 128 + 0 * 32 + fk * 8) ^ sw;
    const int pw1 = (fr * 128 + 1 * 32 + fk * 8) ^ sw;
    const int pw2 = (fr * 128 + 2 * 32 + fk * 8) ^ sw;
    const int pw3 = (fr * 128 + 3 * 32 + fk * 8) ^ sw;
    const int pr0 = (fr * 128 + 0 * 64 + fk * 16) ^ sw;
    const int pr1 = (fr * 128 + 1 * 64 + fk * 16) ^ sw;

    bf16x8 onesf;
    #pragma unroll
    for (int i = 0; i < 8; ++i) onesf[i] = (__bf16)1.0f;

    f32x4 oacc[4][4] = {};
    f32x4 lacc[4] = {};

#define QK8(SA, QI, CB) do {                                                              \
    _Pragma("unroll")                                                                     \
    for (int n_ = 0; n_ < 4; ++n_) {                                                      \
        bf16x8 k0_ = *(const bf16x8*)(KsB + (CB) + kb0 + n_ * 2048);                      \
        bf16x8 k1_ = *(const bf16x8*)(KsB + (CB) + kb1 + n_ * 2048);                      \
        SA[n_] = __builtin_amdgcn_mfma_f32_16x16x32_bf16(k0_, qf[QI][0], SA[n_], 0, 0, 0);\
        SA[n_] = __builtin_amdgcn_mfma_f32_16x16x32_bf16(k1_, qf[QI][1], SA[n_], 0, 0, 0);\
    } } while (0)

#define EXPW(SA, PQ) do {                                                                 \
    _Pragma("unroll")                                                                     \
    for (int n_ = 0; n_ < 4; ++n_) {                                                      \
        bf16x4 pk_;                                                                       \
        _Pragma("unroll")                                                                 \
        for (int r_ = 0; r_ < 4; ++r_)                                                    \
            pk_[r_] = (__bf16)__builtin_amdgcn_exp2f(SA[n_][r_]);                         \
        const int pwn_ = (n_ == 0) ? pw0 : (n_ == 1) ? pw1 : (n_ == 2) ? pw2 : pw3;       \
        *(bf16x4*)(Pw + (PQ) + pwn_) = pk_;                                               \
    } } while (0)

    for (int p = 0; p < 8; ++p) {
        asm volatile("s_waitcnt vmcnt(0)" ::: "memory");
        __builtin_amdgcn_s_barrier();
        __builtin_amdgcn_sched_barrier(0);
        if (p < 7) { STAGE(2 * p + 2); STAGE(2 * p + 3); }

        const int cb0 = ((p & 1) << 1) * 8192;
        const int cb1 = cb0 + 8192;

        bf16x8 vf[4][2];
        #pragma unroll
        for (int nd = 0; nd < 4; ++nd) {
            vf[nd][0] = *(const bf16x8*)(VsB + cb0 + kb0 + nd * 2048);
            vf[nd][1] = *(const bf16x8*)(VsB + cb0 + kb1 + nd * 2048);
        }

        {
            f32x4 s0[4] = {};
            QK8(s0, 0, cb0);
            EXPW(s0, 0);
        }

        #pragma unroll
        for (int j = 0; j < 8; ++j) {
            const int qi = j & 3;
            const int pq = (j & 1) * 2048;
            const int pqn = ((j + 1) & 1) * 2048;
            const int cbn = (j + 1 < 4) ? cb0 : cb1;

            bf16x8 pf0 = *(const bf16x8*)(Pw + pq + pr0);
            bf16x8 pf1 = *(const bf16x8*)(Pw + pq + pr1);

            if (j == 4) {
                #pragma unroll
                for (int nd = 0; nd < 4; ++nd) {
                    vf[nd][0] = *(const bf16x8*)(VsB + cb1 + kb0 + nd * 2048);
                    vf[nd][1] = *(const bf16x8*)(VsB + cb1 + kb1 + nd * 2048);
                }
            }

            f32x4 sn[4] = {};
            if (j < 7) QK8(sn, (j + 1) & 3, cbn);

            lacc[qi] = __builtin_amdgcn_mfma_f32_16x16x32_bf16(pf0, onesf, lacc[qi], 0, 0, 0);
            lacc[qi] = __builtin_amdgcn_mfma_f32_16x16x32_bf16(pf1, onesf, lacc[qi], 0, 0, 0);
            #pragma unroll
            for (int nd = 0; nd < 4; ++nd) {
                oacc[qi][nd] = __builtin_amdgcn_mfma_f32_16x16x32_bf16(pf0, vf[nd][0],
                                                                       oacc[qi][nd], 0, 0, 0);
                oacc[qi][nd] = __builtin_amdgcn_mfma_f32_16x16x32_bf16(pf1, vf[nd][1],
                                                                       oacc[qi][nd], 0, 0, 0);
            }

            if (j < 7) EXPW(sn, pqn);
        }
    }

    #pragma unroll
    for (int qi = 0; qi < 4; ++qi) {
        float inv[4];
        #pragma unroll
        for (int r = 0; r < 4; ++r)
            inv[r] = __builtin_amdgcn_rcpf(lacc[qi][r]);
        #pragma unroll
        for (int nd = 0; nd < 4; ++nd)
            #pragma unroll
            for (int r = 0; r < 4; ++r)
                ao[(size_t)(qrow0 + qi * 16 + fk * 4 + r) * 1024 + h * 64 + nd * 16 + fr] =
                    (__bf16)(oacc[qi][nd][r] * inv[r]);
    }
#undef QK8
#undef EXPW
#undef STAGE
}

// ---------------------------------------------------------------- launch
extern "C" void kernel_launch(void* const* d_in, const int* in_sizes, int n_in,
                              void* d_out, int out_size, void* d_ws, size_t ws_size,
                              hipStream_t stream)
{
    const float* x      = (const float*)d_in[0];
    const float* qkv_w  = (const float*)d_in[1];
    const float* proj_w = (const float*)d_in[2];
    const float* proj_b = (const float*)d_in[3];
    const float* qnw    = (const float*)d_in[4];
    const float* knw    = (const float*)d_in[5];

    char* ws = (char*)d_ws;
    __bf16* xb    = (__bf16*)(ws);                      // 32 MB
    __bf16* wqkv  = (__bf16*)(ws + 33554432);           // 6 MB
    __bf16* wproj = (__bf16*)(ws + 39845888);           // 2 MB
    __bf16* qkv   = (__bf16*)(ws + 41943040);           // 64 MB  [16384][2048] q,k only
    __bf16* vt    = (__bf16*)(ws + 109051904);          // 32 MB  [b][h][d][n]
    __bf16* ao    = (__bf16*)(ws + 142606336);          // 32 MB

    f2b_kernel<<<2048, 256, 0, stream>>>((const float4*)x, (bf16x4*)xb, 16777216 / 4);
    f2b2_kernel<<<2048, 256, 0, stream>>>((const float4*)qkv_w,  (bf16x4*)wqkv,  3145728 / 4,
                                          (const float4*)proj_w, (bf16x4*)wproj, 1048576 / 4);

    gemm256<0><<<768, 512, 0, stream>>>(xb, wqkv, nullptr, qnw, knw,
                                        nullptr, qkv, vt, 16384, 1024, 12, 2048);
    attn_kernel<<<1024, 256, 0, stream>>>(qkv, vt, ao);
    gemm256<1><<<256, 512, 0, stream>>>(ao, wproj, proj_b, nullptr, nullptr,
                                        (float*)d_out, nullptr, nullptr, 16384, 1024, 4, 1024);
}

// Round 23
// 252.494 us; speedup vs baseline: 1.0232x; 1.0035x over previous
//
#include <hip/hip_runtime.h>
#include <hip/hip_bf16.h>

typedef __attribute__((ext_vector_type(8))) __bf16 bf16x8;
typedef __attribute__((ext_vector_type(4))) __bf16 bf16x4;
typedef __attribute__((ext_vector_type(4))) float f32x4;

#define AS1(p) ((__attribute__((address_space(1))) void*)(p))
#define AS3(p) ((__attribute__((address_space(3))) void*)(p))

// ---------------------------------------------------------------- f32 -> bf16
__global__ void f2b_kernel(const float4* __restrict__ in, bf16x4* __restrict__ out, int n4) {
    int idx = blockIdx.x * blockDim.x + threadIdx.x;
    int stride = gridDim.x * blockDim.x;
    for (int i = idx; i < n4; i += stride) {
        float4 v = in[i];
        bf16x4 o;
        o[0] = (__bf16)v.x; o[1] = (__bf16)v.y; o[2] = (__bf16)v.z; o[3] = (__bf16)v.w;
        out[i] = o;
    }
}

// two-buffer variant (weights): one launch instead of two
__global__ void f2b2_kernel(const float4* __restrict__ a, bf16x4* __restrict__ oa, int na4,
                            const float4* __restrict__ b, bf16x4* __restrict__ ob, int nb4) {
    int idx = blockIdx.x * blockDim.x + threadIdx.x;
    int stride = gridDim.x * blockDim.x;
    for (int i = idx; i < na4 + nb4; i += stride) {
        const float4 v = (i < na4) ? a[i] : b[i - na4];
        bf16x4 o;
        o[0] = (__bf16)v.x; o[1] = (__bf16)v.y; o[2] = (__bf16)v.z; o[3] = (__bf16)v.w;
        if (i < na4) oa[i] = o; else ob[i - na4] = o;
    }
}

// ---------------------------------------------------------------- 256x256 pipelined GEMM (r13/r15 best, frozen)
// C = A @ B^T. 512 thr = 8 waves (2M x 4N), per-wave 128x64 output, acc[8][4].
// K in 32-wide slots; 4-slot LDS ring staged 3 ahead (counted vmcnt(8), 1 barrier/slot).
// The vmcnt->s_barrier pair is load-bearing TWICE (r19/r21 lessons): it publishes
// cross-wave DMA completion AND bounds inter-wave drift below the ring distance.
// Pair swizzle (conflict-free, r13): chunk = fk ^ ((row>>1)&3); DMA source pre-swizzled.
// MODE 0: qkv. q,k -> Cb[row][2048] + fused RMSNorm (q * Dh^-0.5 * log2e); v -> Vt.
// MODE 1: f32 out + bias, ldc = N.
template<int MODE>
__global__ __launch_bounds__(512, 2)
void gemm256(const __bf16* __restrict__ A, const __bf16* __restrict__ Bw,
             const float* __restrict__ bias, const float* __restrict__ qw,
             const float* __restrict__ kw, float* __restrict__ Cf,
             __bf16* __restrict__ Cb, __bf16* __restrict__ Vt,
             int M, int K, int nbn, int ldc)
{
    __shared__ __bf16 Asl[4][256 * 32];
    __shared__ __bf16 Bsl[4][256 * 32];
    const int tid = threadIdx.x, l = tid & 63, w = tid >> 6;
    const int fr = l & 15, fk = l >> 4;

    const int cpx = gridDim.x >> 3;
    const int wg = (blockIdx.x & 7) * cpx + (blockIdx.x >> 3);
    const int bm = wg / nbn, bn = wg % nbn;

    const __bf16* Ag = A + (size_t)bm * 256 * K;
    const __bf16* Bg = Bw + (size_t)bn * 256 * K;

    const int arow = tid >> 2;
    const int uch = (tid & 3) ^ ((arow >> 1) & 3);
    const size_t ga = (size_t)arow * K + uch * 8;
    const size_t ga2 = ga + (size_t)128 * K;

    const int axc = (fk ^ ((fr >> 1) & 3)) * 16;
    int aoff[8], boff[4];
    #pragma unroll
    for (int m = 0; m < 8; ++m)
        aoff[m] = ((w >> 2) * 128 + m * 16 + fr) * 64 + axc;
    #pragma unroll
    for (int n = 0; n < 4; ++n)
        boff[n] = ((w & 3) * 64 + n * 16 + fr) * 64 + axc;

    f32x4 acc[8][4] = {};

#define STAGE256(S) do {                                                                    \
    const int sb_ = (S) & 3;                                                                \
    __builtin_amdgcn_global_load_lds(AS1(Ag + (size_t)(S) * 32 + ga),                       \
        AS3((char*)&Asl[sb_][0] + tid * 16), 16, 0, 0);                                     \
    __builtin_amdgcn_global_load_lds(AS1(Ag + (size_t)(S) * 32 + ga2),                      \
        AS3((char*)&Asl[sb_][0] + tid * 16 + 8192), 16, 0, 0);                              \
    __builtin_amdgcn_global_load_lds(AS1(Bg + (size_t)(S) * 32 + ga),                       \
        AS3((char*)&Bsl[sb_][0] + tid * 16), 16, 0, 0);                                     \
    __builtin_amdgcn_global_load_lds(AS1(Bg + (size_t)(S) * 32 + ga2),                      \
        AS3((char*)&Bsl[sb_][0] + tid * 16 + 8192), 16, 0, 0);                              \
} while (0)

#define PHASE256(S, VMSTR, DOSTAGE) do {                                                    \
    asm volatile("s_waitcnt vmcnt(" VMSTR ")" ::: "memory");                                \
    __builtin_amdgcn_s_barrier();                                                           \
    __builtin_amdgcn_sched_barrier(0);                                                      \
    const int pb_ = (S) & 3;                                                                \
    bf16x8 af[8], bfv[4];                                                                   \
    _Pragma("unroll")                                                                       \
    for (int m = 0; m < 8; ++m)                                                             \
        af[m] = *(const bf16x8*)((const char*)&Asl[pb_][0] + aoff[m]);                      \
    _Pragma("unroll")                                                                       \
    for (int n = 0; n < 4; ++n)                                                             \
        bfv[n] = *(const bf16x8*)((const char*)&Bsl[pb_][0] + boff[n]);                     \
    if (DOSTAGE) STAGE256((S) + 3);                                                         \
    __builtin_amdgcn_s_setprio(1);                                                          \
    _Pragma("unroll")                                                                       \
    for (int m = 0; m < 8; ++m)                                                             \
        _Pragma("unroll")                                                                   \
        for (int n = 0; n < 4; ++n)                                                         \
            acc[m][n] = __builtin_amdgcn_mfma_f32_16x16x32_bf16(af[m], bfv[n], acc[m][n], 0, 0, 0); \
    __builtin_amdgcn_s_setprio(0);                                                          \
} while (0)

    const int S = K >> 5;
    STAGE256(0); STAGE256(1); STAGE256(2);
    for (int s = 0; s < S - 2; ++s)
        PHASE256(s, "8", (s + 3 < S));
    PHASE256(S - 2, "4", false);
    PHASE256(S - 1, "0", false);
#undef PHASE256
#undef STAGE256

    // ---------------- epilogue: C/D layout col = fr, row = fk*4 + r
    const int rb0 = bm * 256 + (w >> 2) * 128 + fk * 4;
    const int cb0 = bn * 256 + (w & 3) * 64;

    if (MODE == 1) {
        #pragma unroll
        for (int m = 0; m < 8; ++m)
            #pragma unroll
            for (int n = 0; n < 4; ++n) {
                const int col = cb0 + n * 16 + fr;
                const float bv = bias[col];
                #pragma unroll
                for (int r = 0; r < 4; ++r)
                    Cf[(size_t)(rb0 + m * 16 + r) * ldc + col] = acc[m][n][r] + bv;
            }
    } else {
        const int sect = bn >> 2;          // 0=q, 1=k, 2=v (nbn=12)
        if (sect < 2) {
            const float* wp = (sect == 0) ? qw : kw;
            float wn[4];
            #pragma unroll
            for (int n = 0; n < 4; ++n) wn[n] = wp[((w & 3) * 64 + n * 16 + fr) & 63];
            #pragma unroll
            for (int m = 0; m < 8; ++m) {
                float sc[4];
                #pragma unroll
                for (int r = 0; r < 4; ++r) {
                    float ps = 0.f;
                    #pragma unroll
                    for (int n = 0; n < 4; ++n) ps += acc[m][n][r] * acc[m][n][r];
                    ps += __shfl_xor(ps, 1); ps += __shfl_xor(ps, 2);
                    ps += __shfl_xor(ps, 4); ps += __shfl_xor(ps, 8);
                    sc[r] = rsqrtf(ps * (1.0f / 64.0f) + 1e-6f);
                    if (sect == 0) sc[r] *= 0.18033688011112042f;   // 0.125 * log2(e)
                }
                #pragma unroll
                for (int n = 0; n < 4; ++n)
                    #pragma unroll
                    for (int r = 0; r < 4; ++r)
                        Cb[(size_t)(rb0 + m * 16 + r) * ldc + cb0 + n * 16 + fr] =
                            (__bf16)(acc[m][n][r] * sc[r] * wn[n]);
            }
        } else {
            // v -> Vt[((b*16+h)*64+d)*1024 + token], token-contiguous 8B stores
            #pragma unroll
            for (int m = 0; m < 8; ++m) {
                const int tok = rb0 + m * 16;
                const int b = tok >> 10, ntok = tok & 1023;
                #pragma unroll
                for (int n = 0; n < 4; ++n) {
                    const int vd = (bn - 8) * 256 + (w & 3) * 64 + n * 16 + fr;
                    bf16x4 pk;
                    #pragma unroll
                    for (int r = 0; r < 4; ++r) pk[r] = (__bf16)acc[m][n][r];
                    *(bf16x4*)&Vt[((size_t)((b * 16 + (vd >> 6)) * 64 + (vd & 63))) * 1024 + ntok] = pk;
                }
            }
        }
    }
}

// ---------------------------------------------------------------- flash attention v12 (r18, frozen)
// 4 q-tiles/wave (256 q-rows/block, grid 1024), 2 blocks/CU, kt-pair ring staging.
// Explicit software pipeline over j = kh*4+qi; P parity-buffered; no-max exp2 softmax;
// ls via MFMA against ones fragment.
__global__ __launch_bounds__(256, 2)
void attn_kernel(const __bf16* __restrict__ qkv, const __bf16* __restrict__ vt,
                 __bf16* __restrict__ ao)
{
    __shared__ __bf16 Ks[4][64 * 64];       // 32 KB, ring of 4 kt tiles
    __shared__ __bf16 Vs[4][64 * 64];       // 32 KB
    __shared__ __bf16 Pl[4][2 * 16 * 64];   // 16 KB, per-wave parity-buffered P
    const int tid = threadIdx.x, l = tid & 63, w = tid >> 6;
    const int fr = l & 15, fk = l >> 4;
    const int sw = (fr & 7) << 4;

    const int bi = blockIdx.x;
    const int L = (bi & 7) * 128 + (bi >> 3);
    const int qb = L & 3, h = (L >> 2) & 15, b = L >> 6;

    const __bf16* Kg = qkv + (size_t)b * 1024 * 2048 + 1024 + h * 64;
    const __bf16* Vg = vt + (size_t)((b * 16 + h) * 64) * 1024;
    const int srow = tid >> 3, scp = tid & 7;

    const int c8 = (scp ^ (srow & 7)) * 8;
    const size_t kO0 = (size_t)srow * 2048 + c8, kO1 = kO0 + 32 * 2048;
    const size_t vO0 = (size_t)srow * 1024 + c8, vO1 = vO0 + 32 * 1024;
    char* ksd = (char*)&Ks[0][0] + tid * 16;
    char* vsd = (char*)&Vs[0][0] + tid * 16;

#define STAGE(KT) do {                                                                    \
    char* dk_ = ksd + ((KT) & 3) * 8192;                                                  \
    char* dv_ = vsd + ((KT) & 3) * 8192;                                                  \
    __builtin_amdgcn_global_load_lds(AS1(Kg + (size_t)(KT) * 131072 + kO0), AS3(dk_), 16, 0, 0); \
    __builtin_amdgcn_global_load_lds(AS1(Kg + (size_t)(KT) * 131072 + kO1), AS3(dk_ + 4096), 16, 0, 0); \
    __builtin_amdgcn_global_load_lds(AS1(Vg + (KT) * 64 + vO0), AS3(dv_), 16, 0, 0);      \
    __builtin_amdgcn_global_load_lds(AS1(Vg + (KT) * 64 + vO1), AS3(dv_ + 4096), 16, 0, 0); \
} while (0)

    STAGE(0); STAGE(1);     // pair 0 in flight (8 loads)

    const int qrow0 = b * 1024 + qb * 256 + w * 64;
    bf16x8 qf[4][2];
    #pragma unroll
    for (int qi = 0; qi < 4; ++qi)
        #pragma unroll
        for (int dc = 0; dc < 2; ++dc)
            qf[qi][dc] = *(const bf16x8*)&qkv[(size_t)(qrow0 + qi * 16 + fr) * 2048
                                              + h * 64 + dc * 32 + fk * 8];

    const int kb0 = fr * 128 + ((fk ^ (fr & 7)) * 16);
    const int kb1 = fr * 128 + (((4 + fk) ^ (fr & 7)) * 16);
    const char* KsB = (const char*)&Ks[0][0];
    const char* VsB = (const char*)&Vs[0][0];

    char* Pw = (char*)&Pl[w][0];
    const int pw0 = (fr * 128 + 0 * 32 + fk * 8) ^ sw;
    const int pw1 = (fr * 128 + 1 * 32 + fk * 8) ^ sw;
    const int pw2 = (fr * 128 + 2 * 32 + fk * 8) ^ sw;
    const int pw3 = (fr * 128 + 3 * 32 + fk * 8) ^ sw;
    const int pr0 = (fr * 128 + 0 * 64 + fk * 16) ^ sw;
    const int pr1 = (fr * 128 + 1 * 64 + fk * 16) ^ sw;

    bf16x8 onesf;
    #pragma unroll
    for (int i = 0; i < 8; ++i) onesf[i] = (__bf16)1.0f;

    f32x4 oacc[4][4] = {};
    f32x4 lacc[4] = {};

#define QK8(SA, QI, CB) do {                                                              \
    _Pragma("unroll")                                                                     \
    for (int n_ = 0; n_ < 4; ++n_) {                                                      \
        bf16x8 k0_ = *(const bf16x8*)(KsB + (CB) + kb0 + n_ * 2048);                      \
        bf16x8 k1_ = *(const bf16x8*)(KsB + (CB) + kb1 + n_ * 2048);                      \
        SA[n_] = __builtin_amdgcn_mfma_f32_16x16x32_bf16(k0_, qf[QI][0], SA[n_], 0, 0, 0);\
        SA[n_] = __builtin_amdgcn_mfma_f32_16x16x32_bf16(k1_, qf[QI][1], SA[n_], 0, 0, 0);\
    } } while (0)

#define EXPW(SA, PQ) do {                                                                 \
    _Pragma("unroll")                                                                     \
    for (int n_ = 0; n_ < 4; ++n_) {                                                      \
        bf16x4 pk_;                                                                       \
        _Pragma("unroll")                                                                 \
        for (int r_ = 0; r_ < 4; ++r_)                                                    \
            pk_[r_] = (__bf16)__builtin_amdgcn_exp2f(SA[n_][r_]);                         \
        const int pwn_ = (n_ == 0) ? pw0 : (n_ == 1) ? pw1 : (n_ == 2) ? pw2 : pw3;       \
        *(bf16x4*)(Pw + (PQ) + pwn_) = pk_;                                               \
    } } while (0)

    for (int p = 0; p < 8; ++p) {
        asm volatile("s_waitcnt vmcnt(0)" ::: "memory");
        __builtin_amdgcn_s_barrier();
        __builtin_amdgcn_sched_barrier(0);
        if (p < 7) { STAGE(2 * p + 2); STAGE(2 * p + 3); }

        const int cb0 = ((p & 1) << 1) * 8192;
        const int cb1 = cb0 + 8192;

        bf16x8 vf[4][2];
        #pragma unroll
        for (int nd = 0; nd < 4; ++nd) {
            vf[nd][0] = *(const bf16x8*)(VsB + cb0 + kb0 + nd * 2048);
            vf[nd][1] = *(const bf16x8*)(VsB + cb0 + kb1 + nd * 2048);
        }

        {
            f32x4 s0[4] = {};
            QK8(s0, 0, cb0);
            EXPW(s0, 0);
        }

        #pragma unroll
        for (int j = 0; j < 8; ++j) {
            const int qi = j & 3;
            const int pq = (j & 1) * 2048;
            const int pqn = ((j + 1) & 1) * 2048;
            const int cbn = (j + 1 < 4) ? cb0 : cb1;

            bf16x8 pf0 = *(const bf16x8*)(Pw + pq + pr0);
            bf16x8 pf1 = *(const bf16x8*)(Pw + pq + pr1);

            if (j == 4) {
                #pragma unroll
                for (int nd = 0; nd < 4; ++nd) {
                    vf[nd][0] = *(const bf16x8*)(VsB + cb1 + kb0 + nd * 2048);
                    vf[nd][1] = *(const bf16x8*)(VsB + cb1 + kb1 + nd * 2048);
                }
            }

            f32x4 sn[4] = {};
            if (j < 7) QK8(sn, (j + 1) & 3, cbn);

            lacc[qi] = __builtin_amdgcn_mfma_f32_16x16x32_bf16(pf0, onesf, lacc[qi], 0, 0, 0);
            lacc[qi] = __builtin_amdgcn_mfma_f32_16x16x32_bf16(pf1, onesf, lacc[qi], 0, 0, 0);
            #pragma unroll
            for (int nd = 0; nd < 4; ++nd) {
                oacc[qi][nd] = __builtin_amdgcn_mfma_f32_16x16x32_bf16(pf0, vf[nd][0],
                                                                       oacc[qi][nd], 0, 0, 0);
                oacc[qi][nd] = __builtin_amdgcn_mfma_f32_16x16x32_bf16(pf1, vf[nd][1],
                                                                       oacc[qi][nd], 0, 0, 0);
            }

            if (j < 7) EXPW(sn, pqn);
        }
    }

    #pragma unroll
    for (int qi = 0; qi < 4; ++qi) {
        float inv[4];
        #pragma unroll
        for (int r = 0; r < 4; ++r)
            inv[r] = __builtin_amdgcn_rcpf(lacc[qi][r]);
        #pragma unroll
        for (int nd = 0; nd < 4; ++nd)
            #pragma unroll
            for (int r = 0; r < 4; ++r)
                ao[(size_t)(qrow0 + qi * 16 + fk * 4 + r) * 1024 + h * 64 + nd * 16 + fr] =
                    (__bf16)(oacc[qi][nd][r] * inv[r]);
    }
#undef QK8
#undef EXPW
#undef STAGE
}

// ---------------------------------------------------------------- launch
extern "C" void kernel_launch(void* const* d_in, const int* in_sizes, int n_in,
                              void* d_out, int out_size, void* d_ws, size_t ws_size,
                              hipStream_t stream)
{
    const float* x      = (const float*)d_in[0];
    const float* qkv_w  = (const float*)d_in[1];
    const float* proj_w = (const float*)d_in[2];
    const float* proj_b = (const float*)d_in[3];
    const float* qnw    = (const float*)d_in[4];
    const float* knw    = (const float*)d_in[5];

    char* ws = (char*)d_ws;
    __bf16* xb    = (__bf16*)(ws);                      // 32 MB
    __bf16* wqkv  = (__bf16*)(ws + 33554432);           // 6 MB
    __bf16* wproj = (__bf16*)(ws + 39845888);           // 2 MB
    __bf16* qkv   = (__bf16*)(ws + 41943040);           // 64 MB  [16384][2048] q,k only
    __bf16* vt    = (__bf16*)(ws + 109051904);          // 32 MB  [b][h][d][n]
    __bf16* ao    = (__bf16*)(ws + 142606336);          // 32 MB

    f2b_kernel<<<2048, 256, 0, stream>>>((const float4*)x, (bf16x4*)xb, 16777216 / 4);
    f2b2_kernel<<<2048, 256, 0, stream>>>((const float4*)qkv_w,  (bf16x4*)wqkv,  3145728 / 4,
                                          (const float4*)proj_w, (bf16x4*)wproj, 1048576 / 4);

    gemm256<0><<<768, 512, 0, stream>>>(xb, wqkv, nullptr, qnw, knw,
                                        nullptr, qkv, vt, 16384, 1024, 12, 2048);
    attn_kernel<<<1024, 256, 0, stream>>>(qkv, vt, ao);
    gemm256<1><<<256, 512, 0, stream>>>(ao, wproj, proj_b, nullptr, nullptr,
                                        (float*)d_out, nullptr, nullptr, 16384, 1024, 4, 1024);
}